// Round 4
// baseline (350.466 us; speedup 1.0000x reference)
//
#include <hip/hip_runtime.h>

// Problem constants
#define B_ 8
#define C_ 64
#define H_ 240
#define W_ 320
#define HW_ (H_ * W_)      // 76800
#define HW4_ (HW_ / 4)     // 19200
#define K_ 10
#define ALPHA_ 0.02f
#define DELTA_ 0.5f
#define MIN_WEIGHT_ 50.0f

#define NCH 4              // channels per k1 block (one-hot amortization)
#define CB_ (C_ / NCH)     // 16 channel-blocks
#define Z1 8               // pixel splits in k1 -> 16*8*8 = 1024 blocks
#define CHUNK1 (HW4_ / Z1) // 2400 float4 per slab

#define K3_BLOCKS (B_ * (HW4_ / 64))  // 2400

// Workspace float offsets:
//   [0, 5120)      sums[b*64+c][k]     (atomic accumulated in k1; memset 0)
//   [5120, 5200)   counts[b*10+k]      (memset 0)
//   [5200, 5280)   S2[b*10+k]          (memset 0)
//   [5280, 5360)   Nk[b*10+k]          (memset 0)
//   [5360]         done counter        (memset 0)
//   [5376, 10496)  means[b*64+c][k]    (fully written by k2; no init)
#define OFF_SUMS 0
#define OFF_CNT  5120
#define OFF_S2   5200
#define OFF_NK   5280
#define OFF_DONE 5360
#define OFF_MEANS 5376

// ---------------------------------------------------------------------------
// Kernel 1: masked channel sums + cluster counts (proven round-1 version).
// grid (CB_, B_, Z1), block 256.
// ---------------------------------------------------------------------------
__global__ __launch_bounds__(256) void k1_sums(
    const float* __restrict__ x, const int* __restrict__ cm,
    float* __restrict__ ws) {
  const int cb = blockIdx.x;
  const int b = blockIdx.y;
  const int z = blockIdx.z;
  const int tid = threadIdx.x;
  const int c0 = cb * NCH;

  const int lo = z * CHUNK1;
  const int hi = lo + CHUNK1;

  float* __restrict__ sums = ws + OFF_SUMS;
  float* __restrict__ counts = ws + OFF_CNT;

  const float4* __restrict__ xp =
      (const float4*)(x + (size_t)(b * C_ + c0) * HW_);
  const int4* __restrict__ cp = (const int4*)(cm + (size_t)b * HW_);

  float acc[NCH][K_];
#pragma unroll
  for (int c = 0; c < NCH; ++c)
#pragma unroll
    for (int j = 0; j < K_; ++j) acc[c][j] = 0.f;
  float cnt[K_];
#pragma unroll
  for (int j = 0; j < K_; ++j) cnt[j] = 0.f;
  const bool do_cnt = (cb == 0);

  for (int i = lo + tid; i < hi; i += 256) {
    const int4 k4 = cp[i];
    float oh0[K_], oh1[K_], oh2[K_], oh3[K_];
#pragma unroll
    for (int j = 0; j < K_; ++j) {
      oh0[j] = (k4.x == j) ? 1.f : 0.f;
      oh1[j] = (k4.y == j) ? 1.f : 0.f;
      oh2[j] = (k4.z == j) ? 1.f : 0.f;
      oh3[j] = (k4.w == j) ? 1.f : 0.f;
    }
    if (do_cnt) {
#pragma unroll
      for (int j = 0; j < K_; ++j)
        cnt[j] += (oh0[j] + oh1[j]) + (oh2[j] + oh3[j]);
    }
#pragma unroll
    for (int c = 0; c < NCH; ++c) {
      const float4 v = xp[c * HW4_ + i];
#pragma unroll
      for (int j = 0; j < K_; ++j) {
        acc[c][j] += v.x * oh0[j];
        acc[c][j] += v.y * oh1[j];
        acc[c][j] += v.z * oh2[j];
        acc[c][j] += v.w * oh3[j];
      }
    }
  }

  // wave-level reduce, one atomic per wave per bin
#pragma unroll
  for (int c = 0; c < NCH; ++c) {
#pragma unroll
    for (int j = 0; j < K_; ++j) {
      float v = acc[c][j];
#pragma unroll
      for (int off = 32; off > 0; off >>= 1) v += __shfl_down(v, off, 64);
      if ((tid & 63) == 0)
        atomicAdd(&sums[(b * C_ + c0 + c) * K_ + j], v);
    }
  }
  if (do_cnt) {
#pragma unroll
    for (int j = 0; j < K_; ++j) {
      float v = cnt[j];
#pragma unroll
      for (int off = 32; off > 0; off >>= 1) v += __shfl_down(v, off, 64);
      if ((tid & 63) == 0) atomicAdd(&counts[b * K_ + j], v);
    }
  }
}

// ---------------------------------------------------------------------------
// Kernel 2: means normalization, ONCE per batch (hoisted out of k3's 2400
// blocks). grid (B_), block 256. ~3 µs.
// ---------------------------------------------------------------------------
__global__ __launch_bounds__(256) void k2_norm(float* __restrict__ ws) {
  const int b = blockIdx.x;
  const int tid = threadIdx.x;

  const float* __restrict__ sums = ws + OFF_SUMS + b * C_ * K_;
  const float* __restrict__ counts = ws + OFF_CNT + b * K_;
  float* __restrict__ means = ws + OFF_MEANS + b * C_ * K_;

  __shared__ float mlds[C_ * K_];
  __shared__ float nrm[K_];

  for (int i = tid; i < C_ * K_; i += 256)
    mlds[i] = sums[i] / (counts[i % K_] + 1e-10f);
  __syncthreads();
  if (tid < K_) {
    float n2 = 0.f;
#pragma unroll
    for (int c = 0; c < C_; ++c) {
      const float mm = mlds[c * K_ + tid];
      n2 += mm * mm;
    }
    nrm[tid] = 1.f / fmaxf(sqrtf(n2), 1e-12f);
  }
  __syncthreads();
  for (int i = tid; i < C_ * K_; i += 256)
    means[i] = mlds[i] * nrm[i % K_];
}

// ---------------------------------------------------------------------------
// Kernel 3: per-pixel intra -> S2/Nk. Prologue is now just a 640-float load.
// Last block to finish runs the finalize (hinge + output) inline.
// grid (300, 8), block 256 = 64 pixel-lanes x 4 channel-groups.
// ---------------------------------------------------------------------------
__global__ __launch_bounds__(256) void k3_intra(
    const float* __restrict__ x, const int* __restrict__ cm,
    float* __restrict__ ws, float* __restrict__ out) {
  const int b = blockIdx.y;
  const int chunk = blockIdx.x;
  const int tid = threadIdx.x;
  const int lane_p = tid & 63;
  const int grp = tid >> 6;

  float* __restrict__ S2 = ws + OFF_S2;
  float* __restrict__ Nk = ws + OFF_NK;
  const float* __restrict__ means = ws + OFF_MEANS;

  __shared__ float mlds[C_ * K_];   // 640 floats, [c*10+k]
  __shared__ float4 pd[256];
  __shared__ float s2b[K_];
  __shared__ float nkb[K_];

  // ---- prologue: load normalized means (coalesced, L2-hot) ----
  for (int i = tid; i < C_ * K_; i += 256) mlds[i] = means[b * C_ * K_ + i];
  if (tid < K_) { s2b[tid] = 0.f; nkb[tid] = 0.f; }
  __syncthreads();

  // ---- intra distances ----
  const int p4 = chunk * 64 + lane_p;
  const int4 k4 = ((const int4*)(cm + (size_t)b * HW_))[p4];
  const float4* __restrict__ xb = (const float4*)(x + (size_t)b * C_ * HW_);

  const int c0 = grp * (C_ / 4);
  const float* __restrict__ m0 = &mlds[c0 * K_ + k4.x];
  const float* __restrict__ m1 = &mlds[c0 * K_ + k4.y];
  const float* __restrict__ m2 = &mlds[c0 * K_ + k4.z];
  const float* __restrict__ m3 = &mlds[c0 * K_ + k4.w];

  float d0 = 0.f, d1 = 0.f, d2 = 0.f, d3 = 0.f;
#pragma unroll
  for (int cc = 0; cc < C_ / 4; ++cc) {
    const float4 v = xb[(c0 + cc) * HW4_ + p4];
    d0 += v.x * m0[cc * K_];
    d1 += v.y * m1[cc * K_];
    d2 += v.z * m2[cc * K_];
    d3 += v.w * m3[cc * K_];
  }
  pd[tid] = make_float4(d0, d1, d2, d3);
  __syncthreads();

  if (grp == 0) {
    float4 a = pd[lane_p];
    float4 bb = pd[lane_p + 64];
    float4 cc = pd[lane_p + 128];
    float4 dd = pd[lane_p + 192];
    const float i0 = 0.5f * (1.f - (a.x + bb.x + cc.x + dd.x));
    const float i1 = 0.5f * (1.f - (a.y + bb.y + cc.y + dd.y));
    const float i2 = 0.5f * (1.f - (a.z + bb.z + cc.z + dd.z));
    const float i3 = 0.5f * (1.f - (a.w + bb.w + cc.w + dd.w));

    atomicAdd(&s2b[k4.x], i0 * i0);
    atomicAdd(&s2b[k4.y], i1 * i1);
    atomicAdd(&s2b[k4.z], i2 * i2);
    atomicAdd(&s2b[k4.w], i3 * i3);
    atomicAdd(&nkb[k4.x], i0 > ALPHA_ ? 1.f : 0.f);
    atomicAdd(&nkb[k4.y], i1 > ALPHA_ ? 1.f : 0.f);
    atomicAdd(&nkb[k4.z], i2 > ALPHA_ ? 1.f : 0.f);
    atomicAdd(&nkb[k4.w], i3 > ALPHA_ ? 1.f : 0.f);
  }
  __syncthreads();

  if (tid < K_) {
    atomicAdd(&S2[b * K_ + tid], s2b[tid]);
    atomicAdd(&Nk[b * K_ + tid], nkb[tid]);
  }
  __syncthreads();   // atomics issued by all waves before done-increment

  // ---- last block runs finalize ----
  __shared__ unsigned lastf;
  if (tid == 0) {
    __threadfence();  // release: S2/Nk atomics ordered before 'done'
    lastf = (atomicAdd((unsigned*)(ws + OFF_DONE), 1u) ==
             (unsigned)(K3_BLOCKS - 1))
                ? 1u
                : 0u;
  }
  __syncthreads();
  if (lastf == 0u) return;
  __threadfence();    // acquire: see all blocks' S2/Nk

  // ======================= finalize (former k4) =============================
  float acc_h = 0.f;
  for (int t = tid; t < B_ * 45; t += 256) {
    const int bb = t / 45;
    int idx = t % 45;
    int k = 0, l = 0;
    for (k = 0; k < K_; ++k) {
      const int row = K_ - 1 - k;
      if (idx < row) { l = k + 1 + idx; break; }
      idx -= row;
    }
    float g = 0.f;
    for (int c = 0; c < C_; ++c)
      g += means[(bb * C_ + c) * K_ + k] * means[(bb * C_ + c) * K_ + l];
    const float inter_d = 0.5f * (1.f - g);
    const float h = fmaxf(DELTA_ - inter_d, 0.f);
    acc_h += 2.f * h * h;  // (k,l) and (l,k)
  }

  float acc_i = 0.f, acc_n = 0.f;
  if (tid < B_ * K_) {
    const float nk = Nk[tid];
    acc_n = nk;
    const float w = fmaxf(nk, MIN_WEIGHT_) * (float)K_;
    acc_i = S2[tid] / w;
  }

  __shared__ float rh[256], ri[256], rn[256];
  rh[tid] = acc_h;
  ri[tid] = acc_i;
  rn[tid] = acc_n;
  __syncthreads();
  for (int s = 128; s > 0; s >>= 1) {
    if (tid < s) {
      rh[tid] += rh[tid + s];
      ri[tid] += ri[tid + s];
      rn[tid] += rn[tid + s];
    }
    __syncthreads();
  }
  if (tid == 0) {
    const float inter = rh[0] / (float)((K_ * (K_ - 1) / 2) * B_);
    float intra = ri[0] / (float)B_;
    if (!(rn[0] > 0.f)) intra = 0.f;
    out[0] = intra + inter;
    out[1] = intra;
    out[2] = inter;
  }
}

extern "C" void kernel_launch(void* const* d_in, const int* in_sizes, int n_in,
                              void* d_out, int out_size, void* d_ws, size_t ws_size,
                              hipStream_t stream) {
  const float* x = (const float*)d_in[0];
  const int* cm = (const int*)d_in[1];
  float* ws = (float*)d_ws;

  // Zero sums/counts/S2/Nk/done (5376 floats). means fully written by k2.
  hipMemsetAsync(d_ws, 0, 5376 * sizeof(float), stream);

  k1_sums<<<dim3(CB_, B_, Z1), 256, 0, stream>>>(x, cm, ws);
  k2_norm<<<B_, 256, 0, stream>>>(ws);
  k3_intra<<<dim3(HW4_ / 64, B_), 256, 0, stream>>>(x, cm, ws, (float*)d_out);
}

// Round 5
// 283.386 us; speedup vs baseline: 1.2367x; 1.2367x over previous
//
#include <hip/hip_runtime.h>

// Problem constants
#define B_ 8
#define C_ 64
#define H_ 240
#define W_ 320
#define HW_ (H_ * W_)      // 76800
#define HW4_ (HW_ / 4)     // 19200
#define K_ 10
#define ALPHA_ 0.02f
#define DELTA_ 0.5f
#define MIN_WEIGHT_ 50.0f

#define NCH 4              // channels per k1 block (one-hot amortization)
#define CB_ (C_ / NCH)     // 16 channel-blocks
#define Z1 8               // pixel splits in k1 -> 16*8*8 = 1024 blocks
#define CHUNK1 (HW4_ / Z1) // 2400 float4 per slab

// Workspace float offsets:
//   [0, 5120)      sums[b*64+c][k]   (atomic accumulated in k1; memset 0)
//   [5120, 5200)   counts[b*10+k]    (memset 0)
//   [5200, 5280)   S2[b*10+k]        (memset 0)
//   [5280, 5360)   Nk[b*10+k]        (memset 0)
//   [5360, 10480)  means[b*64+c][k]  (fully written by k2; no init)
#define OFF_SUMS 0
#define OFF_CNT  5120
#define OFF_S2   5200
#define OFF_NK   5280
#define OFF_MEANS 5360

// ---------------------------------------------------------------------------
// Kernel 1: masked channel sums + cluster counts (proven round-1 version,
// byte-for-byte). grid (CB_, B_, Z1), block 256.
// ---------------------------------------------------------------------------
__global__ __launch_bounds__(256) void k1_sums(
    const float* __restrict__ x, const int* __restrict__ cm,
    float* __restrict__ ws) {
  const int cb = blockIdx.x;
  const int b = blockIdx.y;
  const int z = blockIdx.z;
  const int tid = threadIdx.x;
  const int c0 = cb * NCH;

  const int lo = z * CHUNK1;
  const int hi = lo + CHUNK1;

  float* __restrict__ sums = ws + OFF_SUMS;
  float* __restrict__ counts = ws + OFF_CNT;

  const float4* __restrict__ xp =
      (const float4*)(x + (size_t)(b * C_ + c0) * HW_);
  const int4* __restrict__ cp = (const int4*)(cm + (size_t)b * HW_);

  float acc[NCH][K_];
#pragma unroll
  for (int c = 0; c < NCH; ++c)
#pragma unroll
    for (int j = 0; j < K_; ++j) acc[c][j] = 0.f;
  float cnt[K_];
#pragma unroll
  for (int j = 0; j < K_; ++j) cnt[j] = 0.f;
  const bool do_cnt = (cb == 0);

  for (int i = lo + tid; i < hi; i += 256) {
    const int4 k4 = cp[i];
    float oh0[K_], oh1[K_], oh2[K_], oh3[K_];
#pragma unroll
    for (int j = 0; j < K_; ++j) {
      oh0[j] = (k4.x == j) ? 1.f : 0.f;
      oh1[j] = (k4.y == j) ? 1.f : 0.f;
      oh2[j] = (k4.z == j) ? 1.f : 0.f;
      oh3[j] = (k4.w == j) ? 1.f : 0.f;
    }
    if (do_cnt) {
#pragma unroll
      for (int j = 0; j < K_; ++j)
        cnt[j] += (oh0[j] + oh1[j]) + (oh2[j] + oh3[j]);
    }
#pragma unroll
    for (int c = 0; c < NCH; ++c) {
      const float4 v = xp[c * HW4_ + i];
#pragma unroll
      for (int j = 0; j < K_; ++j) {
        acc[c][j] += v.x * oh0[j];
        acc[c][j] += v.y * oh1[j];
        acc[c][j] += v.z * oh2[j];
        acc[c][j] += v.w * oh3[j];
      }
    }
  }

  // wave-level reduce, one atomic per wave per bin
#pragma unroll
  for (int c = 0; c < NCH; ++c) {
#pragma unroll
    for (int j = 0; j < K_; ++j) {
      float v = acc[c][j];
#pragma unroll
      for (int off = 32; off > 0; off >>= 1) v += __shfl_down(v, off, 64);
      if ((tid & 63) == 0)
        atomicAdd(&sums[(b * C_ + c0 + c) * K_ + j], v);
    }
  }
  if (do_cnt) {
#pragma unroll
    for (int j = 0; j < K_; ++j) {
      float v = cnt[j];
#pragma unroll
      for (int off = 32; off > 0; off >>= 1) v += __shfl_down(v, off, 64);
      if ((tid & 63) == 0) atomicAdd(&counts[b * K_ + j], v);
    }
  }
}

// ---------------------------------------------------------------------------
// Kernel 2: means normalization, once per batch. grid (B_), block 256.
// ---------------------------------------------------------------------------
__global__ __launch_bounds__(256) void k2_norm(float* __restrict__ ws) {
  const int b = blockIdx.x;
  const int tid = threadIdx.x;

  const float* __restrict__ sums = ws + OFF_SUMS + b * C_ * K_;
  const float* __restrict__ counts = ws + OFF_CNT + b * K_;
  float* __restrict__ means = ws + OFF_MEANS + b * C_ * K_;

  __shared__ float mlds[C_ * K_];
  __shared__ float nrm[K_];

  for (int i = tid; i < C_ * K_; i += 256)
    mlds[i] = sums[i] / (counts[i % K_] + 1e-10f);
  __syncthreads();
  if (tid < K_) {
    float n2 = 0.f;
#pragma unroll
    for (int c = 0; c < C_; ++c) {
      const float mm = mlds[c * K_ + tid];
      n2 += mm * mm;
    }
    nrm[tid] = 1.f / fmaxf(sqrtf(n2), 1e-12f);
  }
  __syncthreads();
  for (int i = tid; i < C_ * K_; i += 256)
    means[i] = mlds[i] * nrm[i % K_];
}

// ---------------------------------------------------------------------------
// Kernel 3: per-pixel intra -> S2/Nk.  BARRIER-FREE main loop: each thread
// owns one float4 pixel-group and iterates all 64 channels itself — 64
// independent 16B loads, dot finishes in registers, no cross-wave exchange.
// grid (150, 8), block 128 (2 waves).
// ---------------------------------------------------------------------------
__global__ __launch_bounds__(128) void k3_intra(
    const float* __restrict__ x, const int* __restrict__ cm,
    float* __restrict__ ws) {
  const int b = blockIdx.y;
  const int tid = threadIdx.x;
  const int w = tid >> 6;          // wave 0/1

  float* __restrict__ S2 = ws + OFF_S2;
  float* __restrict__ Nk = ws + OFF_NK;
  const float* __restrict__ means = ws + OFF_MEANS;

  __shared__ float mlds[C_ * K_];  // 640 floats, [c*10+k]
  __shared__ float s2w[2 * K_];    // per-wave bins
  __shared__ float nkw[2 * K_];

  for (int i = tid; i < C_ * K_; i += 128) mlds[i] = means[b * C_ * K_ + i];
  if (tid < 2 * K_) { s2w[tid] = 0.f; nkw[tid] = 0.f; }
  __syncthreads();

  const int p4 = blockIdx.x * 128 + tid;  // 0..19199
  const int4 k4 = ((const int4*)(cm + (size_t)b * HW_))[p4];
  const float4* __restrict__ xb =
      (const float4*)(x + (size_t)b * C_ * HW_) + p4;

  // base pointers: channel index folds into ds_read immediate offsets
  const float* __restrict__ m0 = &mlds[k4.x];
  const float* __restrict__ m1 = &mlds[k4.y];
  const float* __restrict__ m2 = &mlds[k4.z];
  const float* __restrict__ m3 = &mlds[k4.w];

  float d0 = 0.f, d1 = 0.f, d2 = 0.f, d3 = 0.f;
#pragma unroll 16
  for (int c = 0; c < C_; ++c) {
    const float4 v = xb[c * HW4_];
    d0 += v.x * m0[c * K_];
    d1 += v.y * m1[c * K_];
    d2 += v.z * m2[c * K_];
    d3 += v.w * m3[c * K_];
  }

  const float i0 = 0.5f * (1.f - d0);
  const float i1 = 0.5f * (1.f - d1);
  const float i2 = 0.5f * (1.f - d2);
  const float i3 = 0.5f * (1.f - d3);

  atomicAdd(&s2w[w * K_ + k4.x], i0 * i0);
  atomicAdd(&s2w[w * K_ + k4.y], i1 * i1);
  atomicAdd(&s2w[w * K_ + k4.z], i2 * i2);
  atomicAdd(&s2w[w * K_ + k4.w], i3 * i3);
  atomicAdd(&nkw[w * K_ + k4.x], i0 > ALPHA_ ? 1.f : 0.f);
  atomicAdd(&nkw[w * K_ + k4.y], i1 > ALPHA_ ? 1.f : 0.f);
  atomicAdd(&nkw[w * K_ + k4.z], i2 > ALPHA_ ? 1.f : 0.f);
  atomicAdd(&nkw[w * K_ + k4.w], i3 > ALPHA_ ? 1.f : 0.f);
  __syncthreads();

  if (tid < K_) {
    atomicAdd(&S2[b * K_ + tid], s2w[tid] + s2w[K_ + tid]);
    atomicAdd(&Nk[b * K_ + tid], nkw[tid] + nkw[K_ + tid]);
  }
}

// ---------------------------------------------------------------------------
// Kernel 4: inter hinge loss + finalize. One block (proven round-1 version).
// ---------------------------------------------------------------------------
__global__ __launch_bounds__(256) void k4_final(
    const float* __restrict__ ws, float* __restrict__ out) {
  const int tid = threadIdx.x;
  const float* __restrict__ means = ws + OFF_MEANS;
  const float* __restrict__ S2 = ws + OFF_S2;
  const float* __restrict__ Nk = ws + OFF_NK;

  float acc_h = 0.f;
  for (int t = tid; t < B_ * 45; t += 256) {
    const int b = t / 45;
    int idx = t % 45;
    int k = 0, l = 0;
    for (k = 0; k < K_; ++k) {
      const int row = K_ - 1 - k;
      if (idx < row) { l = k + 1 + idx; break; }
      idx -= row;
    }
    float g = 0.f;
    for (int c = 0; c < C_; ++c)
      g += means[(b * C_ + c) * K_ + k] * means[(b * C_ + c) * K_ + l];
    const float inter_d = 0.5f * (1.f - g);
    const float h = fmaxf(DELTA_ - inter_d, 0.f);
    acc_h += 2.f * h * h;  // (k,l) and (l,k)
  }

  float acc_i = 0.f, acc_n = 0.f;
  if (tid < B_ * K_) {
    const float nk = Nk[tid];
    acc_n = nk;
    const float w = fmaxf(nk, MIN_WEIGHT_) * (float)K_;
    acc_i = S2[tid] / w;
  }

  __shared__ float rh[256], ri[256], rn[256];
  rh[tid] = acc_h;
  ri[tid] = acc_i;
  rn[tid] = acc_n;
  __syncthreads();
  for (int s = 128; s > 0; s >>= 1) {
    if (tid < s) {
      rh[tid] += rh[tid + s];
      ri[tid] += ri[tid + s];
      rn[tid] += rn[tid + s];
    }
    __syncthreads();
  }
  if (tid == 0) {
    const float inter = rh[0] / (float)((K_ * (K_ - 1) / 2) * B_);
    float intra = ri[0] / (float)B_;
    if (!(rn[0] > 0.f)) intra = 0.f;
    out[0] = intra + inter;
    out[1] = intra;
    out[2] = inter;
  }
}

extern "C" void kernel_launch(void* const* d_in, const int* in_sizes, int n_in,
                              void* d_out, int out_size, void* d_ws, size_t ws_size,
                              hipStream_t stream) {
  const float* x = (const float*)d_in[0];
  const int* cm = (const int*)d_in[1];
  float* ws = (float*)d_ws;

  // Zero sums/counts/S2/Nk (5360 floats). means fully written by k2.
  hipMemsetAsync(d_ws, 0, 5360 * sizeof(float), stream);

  k1_sums<<<dim3(CB_, B_, Z1), 256, 0, stream>>>(x, cm, ws);
  k2_norm<<<B_, 256, 0, stream>>>(ws);
  k3_intra<<<dim3(HW4_ / 128, B_), 128, 0, stream>>>(x, cm, ws);
  k4_final<<<1, 256, 0, stream>>>(ws, (float*)d_out);
}

// Round 6
// 271.891 us; speedup vs baseline: 1.2890x; 1.0423x over previous
//
#include <hip/hip_runtime.h>

// Problem constants
#define B_ 8
#define C_ 64
#define H_ 240
#define W_ 320
#define HW_ (H_ * W_)      // 76800
#define HW4_ (HW_ / 4)     // 19200
#define K_ 10
#define ALPHA_ 0.02f
#define DELTA_ 0.5f
#define MIN_WEIGHT_ 50.0f

#define NCH 4              // channels per k1 block (one-hot amortization)
#define CB_ (C_ / NCH)     // 16 channel-blocks
#define Z1 8               // pixel splits in k1 -> 16*8*8 = 1024 blocks
#define CHUNK1 (HW4_ / Z1) // 2400 float4 per slab

// Workspace float offsets (NO memset anywhere — every word is pure-stored
// before it is read, every accumulator is zeroed by a prior kernel):
//   SL_SUMS [Z1][B*C*K]  per-z partial sums   (pure stores in k1)
//   SL_CNT  [Z1][B*K]    per-z partial counts (pure stores in k1, cb==0)
//   OFF_S2  [B*K]        zeroed by k2, atomics in k3
//   OFF_NK  [B*K]        zeroed by k2, atomics in k3
//   OFF_HP  [B]          per-batch hinge partial (pure store in k2)
//   OFF_MEANS [B*C*K]    normalized means (pure store in k2)
#define SL_SUMS 0
#define SL_CNT  (Z1 * B_ * C_ * K_)          // 40960
#define OFF_S2  (SL_CNT + Z1 * B_ * K_)      // 41600
#define OFF_NK  (OFF_S2 + B_ * K_)           // 41680
#define OFF_HP  (OFF_NK + B_ * K_)           // 41760
#define OFF_MEANS 41792

// ---------------------------------------------------------------------------
// Kernel 1: masked channel sums + cluster counts -> private z-slices.
// Proven main loop (round 1/5); store-only epilogue (round 3) — no atomics,
// so no pre-zeroing of the destination is required.
// grid (CB_, B_, Z1), block 256.
// ---------------------------------------------------------------------------
__global__ __launch_bounds__(256) void k1_sums(
    const float* __restrict__ x, const int* __restrict__ cm,
    float* __restrict__ ws) {
  const int cb = blockIdx.x;
  const int b = blockIdx.y;
  const int z = blockIdx.z;
  const int tid = threadIdx.x;
  const int c0 = cb * NCH;

  const int lo = z * CHUNK1;
  const int hi = lo + CHUNK1;

  const float4* __restrict__ xp =
      (const float4*)(x + (size_t)(b * C_ + c0) * HW_);
  const int4* __restrict__ cp = (const int4*)(cm + (size_t)b * HW_);

  float acc[NCH][K_];
#pragma unroll
  for (int c = 0; c < NCH; ++c)
#pragma unroll
    for (int j = 0; j < K_; ++j) acc[c][j] = 0.f;
  float cnt[K_];
#pragma unroll
  for (int j = 0; j < K_; ++j) cnt[j] = 0.f;
  const bool do_cnt = (cb == 0);

  for (int i = lo + tid; i < hi; i += 256) {
    const int4 k4 = cp[i];
    float oh0[K_], oh1[K_], oh2[K_], oh3[K_];
#pragma unroll
    for (int j = 0; j < K_; ++j) {
      oh0[j] = (k4.x == j) ? 1.f : 0.f;
      oh1[j] = (k4.y == j) ? 1.f : 0.f;
      oh2[j] = (k4.z == j) ? 1.f : 0.f;
      oh3[j] = (k4.w == j) ? 1.f : 0.f;
    }
    if (do_cnt) {
#pragma unroll
      for (int j = 0; j < K_; ++j)
        cnt[j] += (oh0[j] + oh1[j]) + (oh2[j] + oh3[j]);
    }
#pragma unroll
    for (int c = 0; c < NCH; ++c) {
      const float4 v = xp[c * HW4_ + i];
#pragma unroll
      for (int j = 0; j < K_; ++j) {
        acc[c][j] += v.x * oh0[j];
        acc[c][j] += v.y * oh1[j];
        acc[c][j] += v.z * oh2[j];
        acc[c][j] += v.w * oh3[j];
      }
    }
  }

  // wave-level shfl reduce -> LDS partials -> plain stores (no atomics)
  __shared__ float partS[4][NCH * K_];
  __shared__ float partC[4][K_];
  const int w = tid >> 6;
#pragma unroll
  for (int c = 0; c < NCH; ++c) {
#pragma unroll
    for (int j = 0; j < K_; ++j) {
      float v = acc[c][j];
#pragma unroll
      for (int off = 32; off > 0; off >>= 1) v += __shfl_down(v, off, 64);
      if ((tid & 63) == 0) partS[w][c * K_ + j] = v;
    }
  }
  if (do_cnt) {
#pragma unroll
    for (int j = 0; j < K_; ++j) {
      float v = cnt[j];
#pragma unroll
      for (int off = 32; off > 0; off >>= 1) v += __shfl_down(v, off, 64);
      if ((tid & 63) == 0) partC[w][j] = v;
    }
  }
  __syncthreads();

  float* __restrict__ slice =
      ws + SL_SUMS + z * (B_ * C_ * K_) + (b * C_ + c0) * K_;
  if (tid < NCH * K_)
    slice[tid] = (partS[0][tid] + partS[1][tid]) + (partS[2][tid] + partS[3][tid]);
  if (do_cnt && tid < K_) {
    ws[SL_CNT + z * (B_ * K_) + b * K_ + tid] =
        (partC[0][tid] + partC[1][tid]) + (partC[2][tid] + partC[3][tid]);
  }
}

// ---------------------------------------------------------------------------
// Kernel 2: per-batch — reduce z-slices, normalize means, write means,
// compute hinge partial (the former k4 heavy part, means already in LDS),
// zero this batch's S2/Nk bins. grid (B_), block 256.
// ---------------------------------------------------------------------------
__global__ __launch_bounds__(256) void k2_norm(float* __restrict__ ws) {
  const int b = blockIdx.x;
  const int tid = threadIdx.x;

  float* __restrict__ means = ws + OFF_MEANS + b * C_ * K_;

  __shared__ float mlds[C_ * K_];
  __shared__ float cntl[K_];
  __shared__ float nrm[K_];
  __shared__ float hr[64];

  if (tid < K_) {
    float s = 0.f;
#pragma unroll
    for (int z = 0; z < Z1; ++z) s += ws[SL_CNT + z * (B_ * K_) + b * K_ + tid];
    cntl[tid] = s;
    // zero the k3 accumulators for this batch (stream-ordered before k3)
    ws[OFF_S2 + b * K_ + tid] = 0.f;
    ws[OFF_NK + b * K_ + tid] = 0.f;
  }
  __syncthreads();
  for (int i = tid; i < C_ * K_; i += 256) {
    float s = 0.f;
#pragma unroll
    for (int z = 0; z < Z1; ++z)
      s += ws[SL_SUMS + z * (B_ * C_ * K_) + b * C_ * K_ + i];
    mlds[i] = s / (cntl[i % K_] + 1e-10f);
  }
  __syncthreads();
  if (tid < K_) {
    float n2 = 0.f;
#pragma unroll
    for (int c = 0; c < C_; ++c) {
      const float mm = mlds[c * K_ + tid];
      n2 += mm * mm;
    }
    nrm[tid] = 1.f / fmaxf(sqrtf(n2), 1e-12f);
  }
  __syncthreads();
  for (int i = tid; i < C_ * K_; i += 256) {
    const float m = mlds[i] * nrm[i % K_];
    mlds[i] = m;
    means[i] = m;
  }
  __syncthreads();

  // hinge partial: 45 pairs, dots over LDS means
  if (tid < 45) {
    int idx = tid;
    int k = 0, l = 0;
    for (k = 0; k < K_; ++k) {
      const int row = K_ - 1 - k;
      if (idx < row) { l = k + 1 + idx; break; }
      idx -= row;
    }
    float g = 0.f;
#pragma unroll
    for (int c = 0; c < C_; ++c) g += mlds[c * K_ + k] * mlds[c * K_ + l];
    const float inter_d = 0.5f * (1.f - g);
    const float h = fmaxf(DELTA_ - inter_d, 0.f);
    hr[tid] = 2.f * h * h;  // (k,l) and (l,k)
  }
  __syncthreads();
  if (tid == 0) {
    float s = 0.f;
    for (int i = 0; i < 45; ++i) s += hr[i];
    ws[OFF_HP + b] = s;
  }
}

// ---------------------------------------------------------------------------
// Kernel 3: per-pixel intra -> S2/Nk (round-5 winner, byte-for-byte).
// Barrier-free main loop: each thread owns one float4 pixel-group and
// iterates all 64 channels itself. grid (150, 8), block 128 (2 waves).
// ---------------------------------------------------------------------------
__global__ __launch_bounds__(128) void k3_intra(
    const float* __restrict__ x, const int* __restrict__ cm,
    float* __restrict__ ws) {
  const int b = blockIdx.y;
  const int tid = threadIdx.x;
  const int w = tid >> 6;          // wave 0/1

  float* __restrict__ S2 = ws + OFF_S2;
  float* __restrict__ Nk = ws + OFF_NK;
  const float* __restrict__ means = ws + OFF_MEANS;

  __shared__ float mlds[C_ * K_];  // 640 floats, [c*10+k]
  __shared__ float s2w[2 * K_];    // per-wave bins
  __shared__ float nkw[2 * K_];

  for (int i = tid; i < C_ * K_; i += 128) mlds[i] = means[b * C_ * K_ + i];
  if (tid < 2 * K_) { s2w[tid] = 0.f; nkw[tid] = 0.f; }
  __syncthreads();

  const int p4 = blockIdx.x * 128 + tid;  // 0..19199
  const int4 k4 = ((const int4*)(cm + (size_t)b * HW_))[p4];
  const float4* __restrict__ xb =
      (const float4*)(x + (size_t)b * C_ * HW_) + p4;

  const float* __restrict__ m0 = &mlds[k4.x];
  const float* __restrict__ m1 = &mlds[k4.y];
  const float* __restrict__ m2 = &mlds[k4.z];
  const float* __restrict__ m3 = &mlds[k4.w];

  float d0 = 0.f, d1 = 0.f, d2 = 0.f, d3 = 0.f;
#pragma unroll 16
  for (int c = 0; c < C_; ++c) {
    const float4 v = xb[c * HW4_];
    d0 += v.x * m0[c * K_];
    d1 += v.y * m1[c * K_];
    d2 += v.z * m2[c * K_];
    d3 += v.w * m3[c * K_];
  }

  const float i0 = 0.5f * (1.f - d0);
  const float i1 = 0.5f * (1.f - d1);
  const float i2 = 0.5f * (1.f - d2);
  const float i3 = 0.5f * (1.f - d3);

  atomicAdd(&s2w[w * K_ + k4.x], i0 * i0);
  atomicAdd(&s2w[w * K_ + k4.y], i1 * i1);
  atomicAdd(&s2w[w * K_ + k4.z], i2 * i2);
  atomicAdd(&s2w[w * K_ + k4.w], i3 * i3);
  atomicAdd(&nkw[w * K_ + k4.x], i0 > ALPHA_ ? 1.f : 0.f);
  atomicAdd(&nkw[w * K_ + k4.y], i1 > ALPHA_ ? 1.f : 0.f);
  atomicAdd(&nkw[w * K_ + k4.z], i2 > ALPHA_ ? 1.f : 0.f);
  atomicAdd(&nkw[w * K_ + k4.w], i3 > ALPHA_ ? 1.f : 0.f);
  __syncthreads();

  if (tid < K_) {
    atomicAdd(&S2[b * K_ + tid], s2w[tid] + s2w[K_ + tid]);
    atomicAdd(&Nk[b * K_ + tid], nkw[tid] + nkw[K_ + tid]);
  }
}

// ---------------------------------------------------------------------------
// Kernel 4: tiny combine — 80 S2/Nk bins + 8 hinge partials. 1 block x 128.
// ---------------------------------------------------------------------------
__global__ __launch_bounds__(128) void k4_final(
    const float* __restrict__ ws, float* __restrict__ out) {
  const int tid = threadIdx.x;
  const float* __restrict__ S2 = ws + OFF_S2;
  const float* __restrict__ Nk = ws + OFF_NK;
  const float* __restrict__ hp = ws + OFF_HP;

  float acc_i = 0.f, acc_n = 0.f, acc_h = 0.f;
  if (tid < B_ * K_) {
    const float nk = Nk[tid];
    acc_n = nk;
    const float w = fmaxf(nk, MIN_WEIGHT_) * (float)K_;
    acc_i = S2[tid] / w;
  }
  if (tid < B_) acc_h = hp[tid];

  __shared__ float rh[128], ri[128], rn[128];
  rh[tid] = acc_h;
  ri[tid] = acc_i;
  rn[tid] = acc_n;
  __syncthreads();
  for (int s = 64; s > 0; s >>= 1) {
    if (tid < s) {
      rh[tid] += rh[tid + s];
      ri[tid] += ri[tid + s];
      rn[tid] += rn[tid + s];
    }
    __syncthreads();
  }
  if (tid == 0) {
    const float inter = rh[0] / (float)((K_ * (K_ - 1) / 2) * B_);
    float intra = ri[0] / (float)B_;
    if (!(rn[0] > 0.f)) intra = 0.f;
    out[0] = intra + inter;
    out[1] = intra;
    out[2] = inter;
  }
}

extern "C" void kernel_launch(void* const* d_in, const int* in_sizes, int n_in,
                              void* d_out, int out_size, void* d_ws, size_t ws_size,
                              hipStream_t stream) {
  const float* x = (const float*)d_in[0];
  const int* cm = (const int*)d_in[1];
  float* ws = (float*)d_ws;

  // No memset: k1 pure-stores slices; k2 zeroes S2/Nk and writes means/hp.
  k1_sums<<<dim3(CB_, B_, Z1), 256, 0, stream>>>(x, cm, ws);
  k2_norm<<<B_, 256, 0, stream>>>(ws);
  k3_intra<<<dim3(HW4_ / 128, B_), 128, 0, stream>>>(x, cm, ws);
  k4_final<<<1, 128, 0, stream>>>(ws, (float*)d_out);
}